// Round 4
// baseline (202.670 us; speedup 1.0000x reference)
//
#include <hip/hip_runtime.h>
#include <hip/hip_fp8.h>
#include <cstdint>

typedef float f32x4 __attribute__((ext_vector_type(4)));
typedef int i32x8 __attribute__((ext_vector_type(8)));
typedef long long i64;

static constexpr int Mdim = 8192;
static constexpr int Kdim = 4096;
static constexpr int Ndim = 4096;

// ---- 256^2 fine-phase pipelined GEMM ----
static constexpr int BM = 256, BN = 256, BK = 128;  // BK in fp8 bytes
static constexpr int NT = Kdim / BK;                // 32 K-tiles
static constexpr int NWG_M = Mdim / BM;             // 32
static constexpr int NWG_N = Ndim / BN;             // 16
static constexpr int NWG = NWG_M * NWG_N;           // 512 (div by 8)
static_assert(NT >= 4, "pipeline needs >=4 K-tiles");

// ---------------------------------------------------------------------------
__device__ __forceinline__ uint8_t f32_to_e4m3(float f) {
  return (uint8_t)__hip_cvt_float_to_fp8(f, __HIP_SATFINITE, __HIP_E4M3);
}

__global__ __launch_bounds__(256) void quant_fp8_kernel(
    const float* __restrict__ in, uint8_t* __restrict__ out, int n_vec16) {
  const int stride = gridDim.x * blockDim.x;
  for (int i = blockIdx.x * blockDim.x + threadIdx.x; i < n_vec16; i += stride) {
    const float4* src = reinterpret_cast<const float4*>(in) + (size_t)i * 4;
    float4 f0 = src[0], f1 = src[1], f2 = src[2], f3 = src[3];
    const float v[16] = {f0.x, f0.y, f0.z, f0.w, f1.x, f1.y, f1.z, f1.w,
                         f2.x, f2.y, f2.z, f2.w, f3.x, f3.y, f3.z, f3.w};
    union alignas(16) {
      uint32_t u[4];
      uint8_t b[16];
    } r;
#pragma unroll
    for (int j = 0; j < 16; ++j) r.b[j] = f32_to_e4m3(v[j]);
    reinterpret_cast<uint4*>(out)[i] = *reinterpret_cast<const uint4*>(r.u);
  }
}

__device__ __forceinline__ void gload_lds16(const uint8_t* g, uint8_t* l) {
  __builtin_amdgcn_global_load_lds(
      (const __attribute__((address_space(1))) void*)g,
      (__attribute__((address_space(3))) void*)l, 16, 0, 0);
}

__device__ __forceinline__ f32x4 mx_mfma(i32x8 a, i32x8 b, f32x4 c) {
  // fp8 e4m3 A/B, unit e8m0 scales (0x7f) -> identical to non-scaled fp8.
  return __builtin_amdgcn_mfma_scale_f32_16x16x128_f8f6f4(
      a, b, c, 0, 0, 0, 0x7f7f7f7f, 0, 0x7f7f7f7f);
}

// ---------------------------------------------------------------------------
// 256x256, BK=128, 8 waves (2Mx4N), per-wave 128x64 = 8x4 frags of
// mfma_scale_f32_16x16x128. FINE-PHASE schedule (m201-style): per tile,
// 4 phases of {ds_read frags || stage 1 half-tile -> BAR -> lgkmcnt(0) ->
// 8 MFMA (setprio) -> BAR}. Staging: tile kt stages A(kt+1) halves at
// ph0/ph1 (OPPOSITE-parity buffer), B(kt+2) halves at ph2/ph3 (same-parity
// B region dead after ph0 lgkm+BAR). vmcnt(4) once per tile at ph3 (never 0
// until tail). Race proof: a region written at phase p had its last ds_read
// at phase <= p-1, completed via that phase's lgkmcnt(0)-before-BAR2; the
// writer issues after BAR2 -> no WAR. RAW via per-wave vmcnt before BAR2 +
// reader issues after BAR2.
// LDS 16B-chunk XOR swizzle (round-2-verified): linear gload dest,
// pre-swizzled global source, XOR'd ds_read offsets.
// ---------------------------------------------------------------------------
__global__ __launch_bounds__(512, 2) void gemm_fp8_mx_256(
    const uint8_t* __restrict__ Aq, const uint8_t* __restrict__ Bq,
    const float* __restrict__ bias, const float* __restrict__ sa,
    const float* __restrict__ sb, float* __restrict__ C) {
  __shared__ alignas(16) uint8_t sA[2][BM * BK];  // 2 x 32 KiB
  __shared__ alignas(16) uint8_t sB[2][BN * BK];  // 2 x 32 KiB

  int wg = (int)blockIdx.x;
  wg = (wg & 7) * (NWG / 8) + (wg >> 3);  // XCD swizzle (512 % 8 == 0)
  const int bm0 = (wg / NWG_N) * BM;
  const int bn0 = (wg % NWG_N) * BN;

  const int t = (int)threadIdx.x;  // 0..511
  const int lane = t & 63;
  const int wave = t >> 6;
  const int wm = wave >> 2;  // 0..1
  const int wn = wave & 3;   // 0..3

  // Staging: one half-tile = 128 rows x 128 B = 2 calls x (512 thr x 16 B).
  // call i: row = h*128 + i*64 + (t>>3); source chunk pre-swizzled
  // ((row&7)==(srow&7) since 64,128 are multiples of 8).
  const int srow = t >> 3;
  const int sc16 = (t & 7) ^ (srow & 7);
  const uint8_t* aBase = Aq + (size_t)(bm0 + srow) * Kdim + sc16 * 16;
  const uint8_t* bBase = Bq + (size_t)(bn0 + srow) * Kdim + sc16 * 16;
  const int ldsOff = t * 16;

  auto stageA = [&](int buf, int kt, int h) {
    const size_t kb = (size_t)kt * BK;
#pragma unroll
    for (int i = 0; i < 2; ++i)
      gload_lds16(aBase + kb + (size_t)(h * 128 + i * 64) * Kdim,
                  &sA[buf][h * 16384 + i * 8192 + ldsOff]);
  };
  auto stageB = [&](int buf, int kt, int h) {
    const size_t kb = (size_t)kt * BK;
#pragma unroll
    for (int i = 0; i < 2; ++i)
      gload_lds16(bBase + kb + (size_t)(h * 128 + i * 64) * Kdim,
                  &sB[buf][h * 16384 + i * 8192 + ldsOff]);
  };

  // Fragment reads (round-2-verified swizzle)
  const int r7 = lane & 7;
  const int kg = (lane >> 4) * 2;
  const int off0 = (kg ^ r7) * 16;
  const int off1 = ((kg + 1) ^ r7) * 16;
  const int rbA = (wm * 128 + (lane & 15)) * BK;
  const int rbB = (wn * 64 + (lane & 15)) * BK;

  auto ldfrag = [&](const uint8_t* base) -> i32x8 {
    union {
      i32x8 v;
      int4 h[2];
    } u;
    u.h[0] = *reinterpret_cast<const int4*>(base + off0);
    u.h[1] = *reinterpret_cast<const int4*>(base + off1);
    return u.v;
  };

  f32x4 acc[8][4] = {};

  // ---- prologue: tile0 full + B(1); vmcnt(4) leaves B(1) in flight.
  stageA(0, 0, 0);
  stageA(0, 0, 1);
  stageB(0, 0, 0);
  stageB(0, 0, 1);
  stageB(1, 1, 0);
  stageB(1, 1, 1);
  asm volatile("s_waitcnt vmcnt(4)" ::: "memory");
  __builtin_amdgcn_s_barrier();
  __builtin_amdgcn_sched_barrier(0);

#pragma unroll 1
  for (int kt = 0; kt < NT; ++kt) {
    const int c = kt & 1;
    const int cn = c ^ 1;
    const uint8_t* A = &sA[c][0];
    const uint8_t* B = &sB[c][0];

    // ======== phase 0: B all + A frags 0,1 ; stage A(kt+1) half 0
    i32x8 bf[4];
#pragma unroll
    for (int n = 0; n < 4; ++n) bf[n] = ldfrag(B + rbB + n * 16 * BK);
    i32x8 a0 = ldfrag(A + rbA + 0 * 16 * BK);
    i32x8 a1 = ldfrag(A + rbA + 1 * 16 * BK);
    if (kt + 1 < NT) stageA(cn, kt + 1, 0);
    __builtin_amdgcn_s_barrier();
    asm volatile("s_waitcnt lgkmcnt(0)" ::: "memory");
    __builtin_amdgcn_sched_barrier(0);
    __builtin_amdgcn_s_setprio(1);
#pragma unroll
    for (int n = 0; n < 4; ++n) acc[0][n] = mx_mfma(a0, bf[n], acc[0][n]);
#pragma unroll
    for (int n = 0; n < 4; ++n) acc[1][n] = mx_mfma(a1, bf[n], acc[1][n]);
    __builtin_amdgcn_s_setprio(0);
    __builtin_amdgcn_s_barrier();
    __builtin_amdgcn_sched_barrier(0);

    // ======== phase 1: A frags 2,3 ; stage A(kt+1) half 1
    a0 = ldfrag(A + rbA + 2 * 16 * BK);
    a1 = ldfrag(A + rbA + 3 * 16 * BK);
    if (kt + 1 < NT) stageA(cn, kt + 1, 1);
    __builtin_amdgcn_s_barrier();
    asm volatile("s_waitcnt lgkmcnt(0)" ::: "memory");
    __builtin_amdgcn_sched_barrier(0);
    __builtin_amdgcn_s_setprio(1);
#pragma unroll
    for (int n = 0; n < 4; ++n) acc[2][n] = mx_mfma(a0, bf[n], acc[2][n]);
#pragma unroll
    for (int n = 0; n < 4; ++n) acc[3][n] = mx_mfma(a1, bf[n], acc[3][n]);
    __builtin_amdgcn_s_setprio(0);
    __builtin_amdgcn_s_barrier();
    __builtin_amdgcn_sched_barrier(0);

    // ======== phase 2: A frags 4,5 ; stage B(kt+2) half 0
    a0 = ldfrag(A + rbA + 4 * 16 * BK);
    a1 = ldfrag(A + rbA + 5 * 16 * BK);
    if (kt + 2 < NT) stageB(c, kt + 2, 0);
    __builtin_amdgcn_s_barrier();
    asm volatile("s_waitcnt lgkmcnt(0)" ::: "memory");
    __builtin_amdgcn_sched_barrier(0);
    __builtin_amdgcn_s_setprio(1);
#pragma unroll
    for (int n = 0; n < 4; ++n) acc[4][n] = mx_mfma(a0, bf[n], acc[4][n]);
#pragma unroll
    for (int n = 0; n < 4; ++n) acc[5][n] = mx_mfma(a1, bf[n], acc[5][n]);
    __builtin_amdgcn_s_setprio(0);
    __builtin_amdgcn_s_barrier();
    __builtin_amdgcn_sched_barrier(0);

    // ======== phase 3: A frags 6,7 ; stage B(kt+2) half 1 ; counted vmcnt
    a0 = ldfrag(A + rbA + 6 * 16 * BK);
    a1 = ldfrag(A + rbA + 7 * 16 * BK);
    if (kt + 2 < NT) stageB(c, kt + 2, 1);
    __builtin_amdgcn_s_barrier();
    asm volatile("s_waitcnt lgkmcnt(0)" ::: "memory");
    __builtin_amdgcn_sched_barrier(0);
    __builtin_amdgcn_s_setprio(1);
#pragma unroll
    for (int n = 0; n < 4; ++n) acc[6][n] = mx_mfma(a0, bf[n], acc[6][n]);
#pragma unroll
    for (int n = 0; n < 4; ++n) acc[7][n] = mx_mfma(a1, bf[n], acc[7][n]);
    __builtin_amdgcn_s_setprio(0);
    if (kt + 2 < NT) {
      // allowed in flight: B(kt+2) halves staged ph2/ph3 (4 loads);
      // A(kt+1)+everything older guaranteed landed.
      asm volatile("s_waitcnt vmcnt(4)" ::: "memory");
    } else {
      asm volatile("s_waitcnt vmcnt(0)" ::: "memory");  // tail drain
    }
    __builtin_amdgcn_s_barrier();
    __builtin_amdgcn_sched_barrier(0);
  }

  // ---- epilogue (C/D: col = lane&15, row = (lane>>4)*4 + reg)
  const float scale = sa[0] * sb[0];
  const int orow0 = bm0 + wm * 128 + ((lane >> 4) << 2);
  const int ocol0 = bn0 + wn * 64 + (lane & 15);
#pragma unroll
  for (int n = 0; n < 4; ++n) {
    const int col = ocol0 + n * 16;
    const float bv = bias[col];
#pragma unroll
    for (int m = 0; m < 8; ++m) {
      const int row = orow0 + m * 16;
#pragma unroll
      for (int r = 0; r < 4; ++r)
        C[(size_t)(row + r) * Ndim + col] = acc[m][n][r] * scale + bv;
    }
  }
}

// ---------------------------------------------------------------------------
// Fallback (tiny d_ws only): round-1 fused kernel, known-correct.
// ---------------------------------------------------------------------------
__device__ __forceinline__ void stage16_cvt(const float* g, uint8_t* l) {
  const float4* s = reinterpret_cast<const float4*>(g);
  float4 f0 = s[0], f1 = s[1], f2 = s[2], f3 = s[3];
  const float v[16] = {f0.x, f0.y, f0.z, f0.w, f1.x, f1.y, f1.z, f1.w,
                       f2.x, f2.y, f2.z, f2.w, f3.x, f3.y, f3.z, f3.w};
  union alignas(16) {
    uint32_t u[4];
    uint8_t b[16];
  } r;
#pragma unroll
  for (int j = 0; j < 16; ++j) r.b[j] = f32_to_e4m3(v[j]);
  *reinterpret_cast<uint4*>(l) = *reinterpret_cast<const uint4*>(r.u);
}

__global__ __launch_bounds__(256) void gemm_fp8_fused_kernel(
    const float* __restrict__ X, const float* __restrict__ W,
    const float* __restrict__ bias, const float* __restrict__ sa,
    const float* __restrict__ sb, float* __restrict__ C) {
  constexpr int FBM = 128, FBN = 128, FBK = 64;
  constexpr int FNWG_N = Ndim / FBN;
  __shared__ alignas(16) uint8_t As[FBM * FBK];
  __shared__ alignas(16) uint8_t Bs[FBN * FBK];

  int wg = (int)blockIdx.x;
  const int nwg = (Mdim / FBM) * FNWG_N;
  wg = (wg & 7) * (nwg / 8) + (wg >> 3);
  const int bm0 = (wg / FNWG_N) * FBM;
  const int bn0 = (wg % FNWG_N) * FBN;

  const int t = (int)threadIdx.x;
  const int lane = t & 63;
  const int wave = t >> 6;
  const int wm = wave >> 1, wn = wave & 1;

  const int c0 = t, c1 = t + 256;
  const int r0 = c0 >> 2, col0 = (c0 & 3) * 16;
  const int r1 = c1 >> 2, col1 = (c1 & 3) * 16;
  const float* xa0 = X + (size_t)(bm0 + r0) * Kdim + col0;
  const float* xa1 = X + (size_t)(bm0 + r1) * Kdim + col1;
  const float* wb0 = W + (size_t)(bn0 + r0) * Kdim + col0;
  const float* wb1 = W + (size_t)(bn0 + r1) * Kdim + col1;

  const int arow = (wm * 64 + (lane & 15)) * FBK;
  const int brow = (wn * 64 + (lane & 15)) * FBK;
  const int koff = (lane >> 4) * 8;

  f32x4 acc[4][4] = {};

  for (int kt = 0; kt < Kdim / FBK; ++kt) {
    const int kb = kt * FBK;
    stage16_cvt(xa0 + kb, As + c0 * 16);
    stage16_cvt(xa1 + kb, As + c1 * 16);
    stage16_cvt(wb0 + kb, Bs + c0 * 16);
    stage16_cvt(wb1 + kb, Bs + c1 * 16);
    __syncthreads();
#pragma unroll
    for (int kk = 0; kk < FBK / 32; ++kk) {
      i64 a[4], b[4];
#pragma unroll
      for (int m = 0; m < 4; ++m)
        a[m] = *reinterpret_cast<const i64*>(&As[arow + m * 16 * FBK + kk * 32 + koff]);
#pragma unroll
      for (int n = 0; n < 4; ++n)
        b[n] = *reinterpret_cast<const i64*>(&Bs[brow + n * 16 * FBK + kk * 32 + koff]);
#pragma unroll
      for (int m = 0; m < 4; ++m)
#pragma unroll
        for (int n = 0; n < 4; ++n)
          acc[m][n] = __builtin_amdgcn_mfma_f32_16x16x32_fp8_fp8(
              a[m], b[n], acc[m][n], 0, 0, 0);
    }
    __syncthreads();
  }

  const float scale = sa[0] * sb[0];
  const int orow0 = bm0 + wm * 64 + ((lane >> 4) << 2);
  const int ocol0 = bn0 + wn * 64 + (lane & 15);
#pragma unroll
  for (int n = 0; n < 4; ++n) {
    const int col = ocol0 + n * 16;
    const float bv = bias[col];
#pragma unroll
    for (int m = 0; m < 4; ++m) {
      const int row = orow0 + m * 16;
#pragma unroll
      for (int r = 0; r < 4; ++r)
        C[(size_t)(row + r) * Ndim + col] = acc[m][n][r] * scale + bv;
    }
  }
}

// ---------------------------------------------------------------------------
extern "C" void kernel_launch(void* const* d_in, const int* in_sizes, int n_in,
                              void* d_out, int out_size, void* d_ws, size_t ws_size,
                              hipStream_t stream) {
  const float* x = (const float*)d_in[0];      // [M, K]
  const float* w = (const float*)d_in[1];      // [N, K]
  const float* bias = (const float*)d_in[2];   // [N]
  const float* s_in = (const float*)d_in[3];   // scalar
  const float* s_w = (const float*)d_in[4];    // scalar
  float* out = (float*)d_out;                  // [M, N] fp32

  const size_t needA = (size_t)Mdim * Kdim;  // 32 MiB
  const size_t needB = (size_t)Ndim * Kdim;  // 16 MiB

  if (ws_size >= needA + needB) {
    uint8_t* Aq = (uint8_t*)d_ws;
    uint8_t* Bq = Aq + needA;
    quant_fp8_kernel<<<2048, 256, 0, stream>>>(x, Aq, (int)(needA / 16));
    quant_fp8_kernel<<<2048, 256, 0, stream>>>(w, Bq, (int)(needB / 16));
    gemm_fp8_mx_256<<<NWG, 512, 0, stream>>>(Aq, Bq, bias, s_in, s_w, out);
  } else {
    gemm_fp8_fused_kernel<<<(Mdim / 128) * (Ndim / 128), 256, 0, stream>>>(
        x, w, bias, s_in, s_w, out);
  }
}

// Round 5
// 201.351 us; speedup vs baseline: 1.0066x; 1.0066x over previous
//
#include <hip/hip_runtime.h>
#include <hip/hip_fp8.h>
#include <cstdint>

typedef float f32x4 __attribute__((ext_vector_type(4)));
typedef int i32x8 __attribute__((ext_vector_type(8)));
typedef long long i64;

static constexpr int Mdim = 8192;
static constexpr int Kdim = 4096;
static constexpr int Ndim = 4096;

// ---- 256^2 reg-dbuf pipelined GEMM ----
static constexpr int BM = 256, BN = 256, BK = 128;  // BK in fp8 bytes
static constexpr int NT = Kdim / BK;                // 32 K-tiles
static constexpr int NWG_M = Mdim / BM;             // 32
static constexpr int NWG_N = Ndim / BN;             // 16
static constexpr int NWG = NWG_M * NWG_N;           // 512 (div by 8)
static_assert(NT >= 4, "pipeline needs >=4 K-tiles");

// ---------------------------------------------------------------------------
__device__ __forceinline__ uint8_t f32_to_e4m3(float f) {
  return (uint8_t)__hip_cvt_float_to_fp8(f, __HIP_SATFINITE, __HIP_E4M3);
}

__global__ __launch_bounds__(256) void quant_fp8_kernel(
    const float* __restrict__ in, uint8_t* __restrict__ out, int n_vec16) {
  const int stride = gridDim.x * blockDim.x;
  for (int i = blockIdx.x * blockDim.x + threadIdx.x; i < n_vec16; i += stride) {
    const float4* src = reinterpret_cast<const float4*>(in) + (size_t)i * 4;
    float4 f0 = src[0], f1 = src[1], f2 = src[2], f3 = src[3];
    const float v[16] = {f0.x, f0.y, f0.z, f0.w, f1.x, f1.y, f1.z, f1.w,
                         f2.x, f2.y, f2.z, f2.w, f3.x, f3.y, f3.z, f3.w};
    union alignas(16) {
      uint32_t u[4];
      uint8_t b[16];
    } r;
#pragma unroll
    for (int j = 0; j < 16; ++j) r.b[j] = f32_to_e4m3(v[j]);
    reinterpret_cast<uint4*>(out)[i] = *reinterpret_cast<const uint4*>(r.u);
  }
}

__device__ __forceinline__ void gload_lds16(const uint8_t* g, uint8_t* l) {
  __builtin_amdgcn_global_load_lds(
      (const __attribute__((address_space(1))) void*)g,
      (__attribute__((address_space(3))) void*)l, 16, 0, 0);
}

__device__ __forceinline__ f32x4 mx_mfma(i32x8 a, i32x8 b, f32x4 c) {
  // fp8 e4m3 A/B, unit e8m0 scales (0x7f) -> identical to non-scaled fp8.
  return __builtin_amdgcn_mfma_scale_f32_16x16x128_f8f6f4(
      a, b, c, 0, 0, 0, 0x7f7f7f7f, 0, 0x7f7f7f7f);
}

// ---------------------------------------------------------------------------
// 256x256, BK=128, 8 waves (2Mx4N), per-wave 128x64 = 8x4 frags of
// mfma_scale_f32_16x16x128.
//
// REG-DBUF schedule (round-5): per tile, issue ds_reads for fragment group
// g+1 BEFORE the MFMAs of group g; the compiler's counted lgkmcnt then
// overlaps LDS service with MFMA issue (within-wave software pipeline).
// Only 2 barriers/tile:
//   BAR_MID (after chunk0 MFMA): every wave past chunk0 has its bf[] reads
//     hw-complete -> stageB(c,kt+2) may overwrite B[c]. stageA(kt+1) targets
//     the OPPOSITE buffer (no hazard) and is issued at tile top for latency.
//   BAR_END (after chunk3 MFMA + vmcnt(4)): reaching it implies each wave's
//     lgkm drained (hw wait before its chunk3 MFMA) -> next tile's A-writes
//     WAR-safe; vmcnt(4) leaves only B(kt+2)'s 4 loads in flight, so
//     A(kt+1)+B(kt+1) are landed (RAW-safe). Never vmcnt(0) until the tail.
// LDS 16B-chunk XOR swizzle (round-2-verified): linear gload dest,
// pre-swizzled global source, XOR'd ds_read offsets.
// ---------------------------------------------------------------------------
__global__ __launch_bounds__(512, 2) void gemm_fp8_mx_256(
    const uint8_t* __restrict__ Aq, const uint8_t* __restrict__ Bq,
    const float* __restrict__ bias, const float* __restrict__ sa,
    const float* __restrict__ sb, float* __restrict__ C) {
  __shared__ alignas(16) uint8_t sA[2][BM * BK];  // 2 x 32 KiB
  __shared__ alignas(16) uint8_t sB[2][BN * BK];  // 2 x 32 KiB

  int wg = (int)blockIdx.x;
  wg = (wg & 7) * (NWG / 8) + (wg >> 3);  // XCD swizzle (512 % 8 == 0)
  const int bm0 = (wg / NWG_N) * BM;
  const int bn0 = (wg % NWG_N) * BN;

  const int t = (int)threadIdx.x;  // 0..511
  const int lane = t & 63;
  const int wave = t >> 6;
  const int wm = wave >> 2;  // 0..1
  const int wn = wave & 3;   // 0..3

  // Staging: full tile = 4 calls x (512 thr x 16 B). call i: row = i*64+(t>>3)
  const int srow = t >> 3;
  const int sc16 = (t & 7) ^ (srow & 7);  // pre-swizzled source chunk
  const uint8_t* aBase = Aq + (size_t)(bm0 + srow) * Kdim + sc16 * 16;
  const uint8_t* bBase = Bq + (size_t)(bn0 + srow) * Kdim + sc16 * 16;
  const int ldsOff = t * 16;

  auto stageA = [&](int buf, int kt) {
    const size_t kb = (size_t)kt * BK;
#pragma unroll
    for (int i = 0; i < 4; ++i)
      gload_lds16(aBase + kb + (size_t)(i * 64) * Kdim,
                  &sA[buf][i * 8192 + ldsOff]);
  };
  auto stageB = [&](int buf, int kt) {
    const size_t kb = (size_t)kt * BK;
#pragma unroll
    for (int i = 0; i < 4; ++i)
      gload_lds16(bBase + kb + (size_t)(i * 64) * Kdim,
                  &sB[buf][i * 8192 + ldsOff]);
  };

  // Fragment reads (round-2-verified swizzle)
  const int r7 = lane & 7;
  const int kg = (lane >> 4) * 2;
  const int off0 = (kg ^ r7) * 16;
  const int off1 = ((kg + 1) ^ r7) * 16;
  const int rbA = (wm * 128 + (lane & 15)) * BK;
  const int rbB = (wn * 64 + (lane & 15)) * BK;

  auto ldfrag = [&](const uint8_t* base) -> i32x8 {
    union {
      i32x8 v;
      int4 h[2];
    } u;
    u.h[0] = *reinterpret_cast<const int4*>(base + off0);
    u.h[1] = *reinterpret_cast<const int4*>(base + off1);
    return u.v;
  };

  f32x4 acc[8][4] = {};

  // ---- prologue: tile0 full + B(1). Order: A0(4), B0(4), B1(4).
  stageA(0, 0);
  stageB(0, 0);
  stageB(1, 1);
  asm volatile("s_waitcnt vmcnt(4)" ::: "memory");  // A0,B0 landed; B1 fly
  __builtin_amdgcn_s_barrier();
  __builtin_amdgcn_sched_barrier(0);

#pragma unroll 1
  for (int kt = 0; kt < NT; ++kt) {
    const int c = kt & 1;
    const int cn = c ^ 1;
    const uint8_t* A = &sA[c][0];
    const uint8_t* B = &sB[c][0];

    // tile top: A(kt+1) into OPPOSITE buffer — no hazard, early for latency
    if (kt + 1 < NT) stageA(cn, kt + 1);

    // read group 0 (bf + a01) and prefetch group 1 (a23)
    i32x8 bf0 = ldfrag(B + rbB + 0 * 16 * BK);
    i32x8 bf1 = ldfrag(B + rbB + 1 * 16 * BK);
    i32x8 bf2 = ldfrag(B + rbB + 2 * 16 * BK);
    i32x8 bf3 = ldfrag(B + rbB + 3 * 16 * BK);
    i32x8 a0 = ldfrag(A + rbA + 0 * 16 * BK);
    i32x8 a1 = ldfrag(A + rbA + 1 * 16 * BK);
    i32x8 a2 = ldfrag(A + rbA + 2 * 16 * BK);
    i32x8 a3 = ldfrag(A + rbA + 3 * 16 * BK);
    __builtin_amdgcn_sched_barrier(0);

    // chunk0 (compiler waits lgkmcnt(4): a2,a3 still outstanding)
    __builtin_amdgcn_s_setprio(1);
    acc[0][0] = mx_mfma(a0, bf0, acc[0][0]);
    acc[0][1] = mx_mfma(a0, bf1, acc[0][1]);
    acc[0][2] = mx_mfma(a0, bf2, acc[0][2]);
    acc[0][3] = mx_mfma(a0, bf3, acc[0][3]);
    acc[1][0] = mx_mfma(a1, bf0, acc[1][0]);
    acc[1][1] = mx_mfma(a1, bf1, acc[1][1]);
    acc[1][2] = mx_mfma(a1, bf2, acc[1][2]);
    acc[1][3] = mx_mfma(a1, bf3, acc[1][3]);
    __builtin_amdgcn_s_setprio(0);

    // BAR_MID: all waves' bf reads complete -> B[c] overwrite is safe
    __builtin_amdgcn_s_barrier();
    if (kt + 2 < NT) stageB(c, kt + 2);
    __builtin_amdgcn_sched_barrier(0);

    // prefetch group 2 (a45)
    i32x8 a4 = ldfrag(A + rbA + 4 * 16 * BK);
    i32x8 a5 = ldfrag(A + rbA + 5 * 16 * BK);
    __builtin_amdgcn_sched_barrier(0);

    // chunk1 (uses a2,a3; a4,a5 outstanding)
    __builtin_amdgcn_s_setprio(1);
    acc[2][0] = mx_mfma(a2, bf0, acc[2][0]);
    acc[2][1] = mx_mfma(a2, bf1, acc[2][1]);
    acc[2][2] = mx_mfma(a2, bf2, acc[2][2]);
    acc[2][3] = mx_mfma(a2, bf3, acc[2][3]);
    acc[3][0] = mx_mfma(a3, bf0, acc[3][0]);
    acc[3][1] = mx_mfma(a3, bf1, acc[3][1]);
    acc[3][2] = mx_mfma(a3, bf2, acc[3][2]);
    acc[3][3] = mx_mfma(a3, bf3, acc[3][3]);
    __builtin_amdgcn_s_setprio(0);

    // prefetch group 3 (a67)
    i32x8 a6 = ldfrag(A + rbA + 6 * 16 * BK);
    i32x8 a7 = ldfrag(A + rbA + 7 * 16 * BK);
    __builtin_amdgcn_sched_barrier(0);

    // chunk2 (uses a4,a5; a6,a7 outstanding)
    __builtin_amdgcn_s_setprio(1);
    acc[4][0] = mx_mfma(a4, bf0, acc[4][0]);
    acc[4][1] = mx_mfma(a4, bf1, acc[4][1]);
    acc[4][2] = mx_mfma(a4, bf2, acc[4][2]);
    acc[4][3] = mx_mfma(a4, bf3, acc[4][3]);
    acc[5][0] = mx_mfma(a5, bf0, acc[5][0]);
    acc[5][1] = mx_mfma(a5, bf1, acc[5][1]);
    acc[5][2] = mx_mfma(a5, bf2, acc[5][2]);
    acc[5][3] = mx_mfma(a5, bf3, acc[5][3]);
    __builtin_amdgcn_s_setprio(0);

    // chunk3 (uses a6,a7; lgkmcnt(0) auto-inserted)
    __builtin_amdgcn_s_setprio(1);
    acc[6][0] = mx_mfma(a6, bf0, acc[6][0]);
    acc[6][1] = mx_mfma(a6, bf1, acc[6][1]);
    acc[6][2] = mx_mfma(a6, bf2, acc[6][2]);
    acc[6][3] = mx_mfma(a6, bf3, acc[6][3]);
    acc[7][0] = mx_mfma(a7, bf0, acc[7][0]);
    acc[7][1] = mx_mfma(a7, bf1, acc[7][1]);
    acc[7][2] = mx_mfma(a7, bf2, acc[7][2]);
    acc[7][3] = mx_mfma(a7, bf3, acc[7][3]);
    __builtin_amdgcn_s_setprio(0);

    // BAR_END: swap buffers. In flight (issue order): ..., B(kt+1)@mid(kt-1),
    // A(kt+1)@top(kt), B(kt+2)@mid(kt). vmcnt(4) -> A(kt+1),B(kt+1) landed.
    if (kt + 2 < NT) {
      asm volatile("s_waitcnt vmcnt(4)" ::: "memory");
    } else {
      asm volatile("s_waitcnt vmcnt(0)" ::: "memory");  // tail drain
    }
    __builtin_amdgcn_s_barrier();
    __builtin_amdgcn_sched_barrier(0);
  }

  // ---- epilogue (C/D: col = lane&15, row = (lane>>4)*4 + reg)
  const float scale = sa[0] * sb[0];
  const int orow0 = bm0 + wm * 128 + ((lane >> 4) << 2);
  const int ocol0 = bn0 + wn * 64 + (lane & 15);
#pragma unroll
  for (int n = 0; n < 4; ++n) {
    const int col = ocol0 + n * 16;
    const float bv = bias[col];
#pragma unroll
    for (int m = 0; m < 8; ++m) {
      const int row = orow0 + m * 16;
#pragma unroll
      for (int r = 0; r < 4; ++r)
        C[(size_t)(row + r) * Ndim + col] = acc[m][n][r] * scale + bv;
    }
  }
}

// ---------------------------------------------------------------------------
// Fallback (tiny d_ws only): round-1 fused kernel, known-correct.
// ---------------------------------------------------------------------------
__device__ __forceinline__ void stage16_cvt(const float* g, uint8_t* l) {
  const float4* s = reinterpret_cast<const float4*>(g);
  float4 f0 = s[0], f1 = s[1], f2 = s[2], f3 = s[3];
  const float v[16] = {f0.x, f0.y, f0.z, f0.w, f1.x, f1.y, f1.z, f1.w,
                       f2.x, f2.y, f2.z, f2.w, f3.x, f3.y, f3.z, f3.w};
  union alignas(16) {
    uint32_t u[4];
    uint8_t b[16];
  } r;
#pragma unroll
  for (int j = 0; j < 16; ++j) r.b[j] = f32_to_e4m3(v[j]);
  *reinterpret_cast<uint4*>(l) = *reinterpret_cast<const uint4*>(r.u);
}

__global__ __launch_bounds__(256) void gemm_fp8_fused_kernel(
    const float* __restrict__ X, const float* __restrict__ W,
    const float* __restrict__ bias, const float* __restrict__ sa,
    const float* __restrict__ sb, float* __restrict__ C) {
  constexpr int FBM = 128, FBN = 128, FBK = 64;
  constexpr int FNWG_N = Ndim / FBN;
  __shared__ alignas(16) uint8_t As[FBM * FBK];
  __shared__ alignas(16) uint8_t Bs[FBN * FBK];

  int wg = (int)blockIdx.x;
  const int nwg = (Mdim / FBM) * FNWG_N;
  wg = (wg & 7) * (nwg / 8) + (wg >> 3);
  const int bm0 = (wg / FNWG_N) * FBM;
  const int bn0 = (wg % FNWG_N) * FBN;

  const int t = (int)threadIdx.x;
  const int lane = t & 63;
  const int wave = t >> 6;
  const int wm = wave >> 1, wn = wave & 1;

  const int c0 = t, c1 = t + 256;
  const int r0 = c0 >> 2, col0 = (c0 & 3) * 16;
  const int r1 = c1 >> 2, col1 = (c1 & 3) * 16;
  const float* xa0 = X + (size_t)(bm0 + r0) * Kdim + col0;
  const float* xa1 = X + (size_t)(bm0 + r1) * Kdim + col1;
  const float* wb0 = W + (size_t)(bn0 + r0) * Kdim + col0;
  const float* wb1 = W + (size_t)(bn0 + r1) * Kdim + col1;

  const int arow = (wm * 64 + (lane & 15)) * FBK;
  const int brow = (wn * 64 + (lane & 15)) * FBK;
  const int koff = (lane >> 4) * 8;

  f32x4 acc[4][4] = {};

  for (int kt = 0; kt < Kdim / FBK; ++kt) {
    const int kb = kt * FBK;
    stage16_cvt(xa0 + kb, As + c0 * 16);
    stage16_cvt(xa1 + kb, As + c1 * 16);
    stage16_cvt(wb0 + kb, Bs + c0 * 16);
    stage16_cvt(wb1 + kb, Bs + c1 * 16);
    __syncthreads();
#pragma unroll
    for (int kk = 0; kk < FBK / 32; ++kk) {
      i64 a[4], b[4];
#pragma unroll
      for (int m = 0; m < 4; ++m)
        a[m] = *reinterpret_cast<const i64*>(&As[arow + m * 16 * FBK + kk * 32 + koff]);
#pragma unroll
      for (int n = 0; n < 4; ++n)
        b[n] = *reinterpret_cast<const i64*>(&Bs[brow + n * 16 * FBK + kk * 32 + koff]);
#pragma unroll
      for (int m = 0; m < 4; ++m)
#pragma unroll
        for (int n = 0; n < 4; ++n)
          acc[m][n] = __builtin_amdgcn_mfma_f32_16x16x32_fp8_fp8(
              a[m], b[n], acc[m][n], 0, 0, 0);
    }
    __syncthreads();
  }

  const float scale = sa[0] * sb[0];
  const int orow0 = bm0 + wm * 64 + ((lane >> 4) << 2);
  const int ocol0 = bn0 + wn * 64 + (lane & 15);
#pragma unroll
  for (int n = 0; n < 4; ++n) {
    const int col = ocol0 + n * 16;
    const float bv = bias[col];
#pragma unroll
    for (int m = 0; m < 4; ++m) {
      const int row = orow0 + m * 16;
#pragma unroll
      for (int r = 0; r < 4; ++r)
        C[(size_t)(row + r) * Ndim + col] = acc[m][n][r] * scale + bv;
    }
  }
}

// ---------------------------------------------------------------------------
extern "C" void kernel_launch(void* const* d_in, const int* in_sizes, int n_in,
                              void* d_out, int out_size, void* d_ws, size_t ws_size,
                              hipStream_t stream) {
  const float* x = (const float*)d_in[0];      // [M, K]
  const float* w = (const float*)d_in[1];      // [N, K]
  const float* bias = (const float*)d_in[2];   // [N]
  const float* s_in = (const float*)d_in[3];   // scalar
  const float* s_w = (const float*)d_in[4];    // scalar
  float* out = (float*)d_out;                  // [M, N] fp32

  const size_t needA = (size_t)Mdim * Kdim;  // 32 MiB
  const size_t needB = (size_t)Ndim * Kdim;  // 16 MiB

  if (ws_size >= needA + needB) {
    uint8_t* Aq = (uint8_t*)d_ws;
    uint8_t* Bq = Aq + needA;
    quant_fp8_kernel<<<2048, 256, 0, stream>>>(x, Aq, (int)(needA / 16));
    quant_fp8_kernel<<<2048, 256, 0, stream>>>(w, Bq, (int)(needB / 16));
    gemm_fp8_mx_256<<<NWG, 512, 0, stream>>>(Aq, Bq, bias, s_in, s_w, out);
  } else {
    gemm_fp8_fused_kernel<<<(Mdim / 128) * (Ndim / 128), 256, 0, stream>>>(
        x, w, bias, s_in, s_w, out);
  }
}